// Round 10
// baseline (761.640 us; speedup 1.0000x reference)
//
#include <hip/hip_runtime.h>
#include <math.h>

#define NN    100000
#define NE    3200000
#define FEAT  128
#define HID   16
#define NCLS  20
#define NBK2  1563           // ceil(NN/64) buckets of 64 dst nodes (dst>>6)
#define NBLKC 512            // blocks for bucket count/scatter
#define TB    1024           // threads/block for kA/kB/kC
#define CHNK  ((NE + NBLKC - 1) / NBLKC)   // 6250 edges per kC block
#define TPB   256            // prop threads/block

typedef _Float16 hf;
typedef _Float16 hf2 __attribute__((ext_vector_type(2)));
typedef _Float16 hf8 __attribute__((ext_vector_type(8)));

__device__ __forceinline__ float dot2f(hf2 a, hf2 b, float c) {
#if defined(__has_builtin) && __has_builtin(__builtin_amdgcn_fdot2)
  return __builtin_amdgcn_fdot2(a, b, c, false);
#else
  return fmaf((float)a.y, (float)b.y, fmaf((float)a.x, (float)b.x, c));
#endif
}

// ---- embedding gather + MLP -> fp16 features + invn ------------------------
__global__ __launch_bounds__(256) void k_embed_mlp(
    const int* __restrict__ ids, const float* __restrict__ emb,
    const float* __restrict__ W1, const float* __restrict__ b1,
    hf* __restrict__ hx, float* __restrict__ invn) {
  __shared__ float sW[FEAT * HID];
  for (int i = threadIdx.x; i < FEAT * HID; i += 256) sW[i] = W1[i];
  __syncthreads();
  int node = blockIdx.x * 16 + (threadIdx.x >> 4);
  int k = threadIdx.x & 15;
  if (node >= NN) return;
  const float* er = emb + (size_t)ids[node] * FEAT;
  float acc = b1[k];
#pragma unroll 8
  for (int j = 0; j < FEAT; ++j) acc = fmaf(er[j], sW[j * HID + k], acc);
  acc = fmaxf(acc, 0.0f);
  hf h = (hf)acc;
  float a = (float)h;
  float n2 = a * a;
  n2 += __shfl_xor(n2, 1); n2 += __shfl_xor(n2, 2);
  n2 += __shfl_xor(n2, 4); n2 += __shfl_xor(n2, 8);
  hx[node * HID + k] = h;
  if (k == 0) invn[node] = rsqrtf(fmaxf(n2, 1e-24f));  // 1/max(||x||,1e-12)
}

// ---------------- bucket build: hist / scan / local-sort scatter ------------
__global__ __launch_bounds__(256) void k_zero(int* __restrict__ c, int n) {
  int i = blockIdx.x * 256 + threadIdx.x;
  if (i < n) c[i] = 0;
}

__global__ __launch_bounds__(TB) void kA(
    const int* __restrict__ edst, int* __restrict__ gcount) {
  __shared__ int h[NBK2];
  for (int i = threadIdx.x; i < NBK2; i += TB) h[i] = 0;
  __syncthreads();
  int s0 = blockIdx.x * CHNK, s1 = min(NE, s0 + CHNK);
  for (int i = s0 + threadIdx.x; i < s1; i += TB)
    atomicAdd(&h[__builtin_nontemporal_load(edst + i) >> 6], 1);
  __syncthreads();
  for (int i = threadIdx.x; i < NBK2; i += TB)
    if (h[i]) atomicAdd(&gcount[i], h[i]);
}

// scan bucket counts -> gbase/gcur (2-chunk Hillis-Steele, NBK2 <= 2*TB)
__global__ __launch_bounds__(TB) void kB(
    const int* __restrict__ gcount, int* __restrict__ gbase,
    int* __restrict__ gcur) {
  __shared__ int sd[TB];
  int tid = threadIdx.x;
  int carry = 0;
  for (int c = 0; c < 2; ++c) {
    int idx = c * TB + tid;
    int v = (idx < NBK2) ? gcount[idx] : 0;
    sd[tid] = v;
    __syncthreads();
    for (int off = 1; off < TB; off <<= 1) {
      int t = (tid >= off) ? sd[tid - off] : 0;
      __syncthreads();
      sd[tid] += t;
      __syncthreads();
    }
    if (idx < NBK2) { int b = carry + sd[tid] - v; gbase[idx] = b; gcur[idx] = b; }
    carry += sd[TB - 1];
    __syncthreads();
  }
}

// kC: block-local LDS counting sort, then COALESCED run write-out to strm.
__global__ __launch_bounds__(TB) void kC(
    const int* __restrict__ esrc, const int* __restrict__ edst,
    int* __restrict__ gcur, unsigned* __restrict__ strm) {
  __shared__ int h[NBK2];            // counts, then scatter cursors
  __shared__ int lofs[NBK2 + 1];     // local exclusive offsets
  __shared__ int basel[NBK2];        // reserved global run bases
  __shared__ int sd[TB];
  __shared__ unsigned lsort[CHNK];   // 25 KB locally sorted chunk
  int tid = threadIdx.x;
  for (int i = tid; i < NBK2; i += TB) h[i] = 0;
  __syncthreads();
  int s0 = blockIdx.x * CHNK, s1 = min(NE, s0 + CHNK);
  int total = s1 - s0;
  for (int i = s0 + tid; i < s1; i += TB)
    atomicAdd(&h[__builtin_nontemporal_load(edst + i) >> 6], 1);
  __syncthreads();                                   // hist complete
  int carry = 0;
  for (int c = 0; c < 2; ++c) {                      // scan h -> lofs
    int idx = c * TB + tid;
    int v = (idx < NBK2) ? h[idx] : 0;
    sd[tid] = v;
    __syncthreads();
    for (int off = 1; off < TB; off <<= 1) {
      int t = (tid >= off) ? sd[tid - off] : 0;
      __syncthreads();
      sd[tid] += t;
      __syncthreads();
    }
    if (idx < NBK2) lofs[idx] = carry + sd[tid] - v;
    carry += sd[TB - 1];
    __syncthreads();
  }
  if (tid == 0) lofs[NBK2] = total;
  for (int i = tid; i < NBK2; i += TB) {             // reserve global runs
    int c2 = h[i];
    basel[i] = c2 ? atomicAdd(&gcur[i], c2) : 0;
  }
  __syncthreads();
  for (int i = tid; i < NBK2; i += TB) h[i] = 0;     // cursors
  __syncthreads();
  for (int i = s0 + tid; i < s1; i += TB) {          // scatter into LDS
    int d = __builtin_nontemporal_load(edst + i);
    int b = d >> 6;
    int p = lofs[b] + atomicAdd(&h[b], 1);
    lsort[p] = (unsigned)__builtin_nontemporal_load(esrc + i) |
               ((unsigned)(d & 63) << 17);
  }
  __syncthreads();                                   // lsort ready
  for (int j = tid; j < total; j += TB) {            // coalesced write-out
    int lo = 0, hi = NBK2;                           // lofs[lo]<=j<lofs[hi]
    while (hi - lo > 1) {
      int mid = (lo + hi) >> 1;
      if (lofs[mid] <= j) lo = mid; else hi = mid;
    }
    strm[basel[lo] + (j - lofs[lo])] = lsort[j];
  }
}

// ---- bucket-centric fused AGNN prop (no fine sort, no col, no kD) ----------
// Block = one 64-dst-node bucket. Stage xn_dst in LDS; one THREAD per edge:
// full 16-wide dot via chained fdot2 (no shfl, one exp/edge), accumulate into
// LDS acc[dlow][k] (stride 17 pads banks) + s[dlow] via ds_add_f32.
__global__ __launch_bounds__(TPB) void k_prop(
    const int* __restrict__ gcount, const int* __restrict__ gbase,
    const unsigned* __restrict__ strm,
    const hf* __restrict__ hx, const float* __restrict__ invn,
    const float* __restrict__ beta_p,
    hf* __restrict__ hxo, float* __restrict__ invno) {
  __shared__ float acc[64 * 17];     // padded: bank = (dl*17+k)%32 spreads
  __shared__ float ssum[64];
  __shared__ hf xn[64 * 18];         // row stride 18 hf = 9 dwords (odd)
  int b = blockIdx.x, tid = threadIdx.x;
  float beta = beta_p ? beta_p[0] : 1.0f;
  int base = gbase[b], n = gcount[b];
  int n0 = b << 6;
  // preload 64 dst nodes; fold in the self-loop term directly
  for (int it = 0; it < 4; ++it) {
    int node = (tid >> 4) + (it << 4);
    int k = tid & 15;
    int gn = n0 + node;
    float x = 0.f, iv = 1.f;
    if (gn < NN) { x = (float)hx[gn * HID + k]; iv = invn[gn]; }
    xn[node * 18 + k] = (hf)(x * iv);
    float n2 = x * x;
    n2 += __shfl_xor(n2, 1); n2 += __shfl_xor(n2, 2);
    n2 += __shfl_xor(n2, 4); n2 += __shfl_xor(n2, 8);
    float es = __expf(beta * n2 * iv * iv);    // exp(beta*||xn||^2)
    acc[node * 17 + k] = es * x;               // self-loop contribution
    if (k == 0) ssum[node] = es;
  }
  __syncthreads();
  const hf8* H8 = (const hf8*)hx;
  const hf2* XN = (const hf2*)xn;
  for (int i = tid; i < n; i += TPB) {
    unsigned w = strm[base + i];               // coalesced stream
    int dl = w >> 17;                          // dst & 63
    int src = w & 0x1FFFF;
    hf8 lo = H8[src * 2], hi = H8[src * 2 + 1];
    float iv = invn[src];
    const hf2* xr = XN + dl * 9;
    float d = 0.f;
    d = dot2f(__builtin_shufflevector(lo, lo, 0, 1), xr[0], d);
    d = dot2f(__builtin_shufflevector(lo, lo, 2, 3), xr[1], d);
    d = dot2f(__builtin_shufflevector(lo, lo, 4, 5), xr[2], d);
    d = dot2f(__builtin_shufflevector(lo, lo, 6, 7), xr[3], d);
    d = dot2f(__builtin_shufflevector(hi, hi, 0, 1), xr[4], d);
    d = dot2f(__builtin_shufflevector(hi, hi, 2, 3), xr[5], d);
    d = dot2f(__builtin_shufflevector(hi, hi, 4, 5), xr[6], d);
    d = dot2f(__builtin_shufflevector(hi, hi, 6, 7), xr[7], d);
    float e = __expf(beta * d * iv);
    atomicAdd(&ssum[dl], e);
    float* ar = &acc[dl * 17];
    atomicAdd(ar + 0,  e * (float)lo[0]);
    atomicAdd(ar + 1,  e * (float)lo[1]);
    atomicAdd(ar + 2,  e * (float)lo[2]);
    atomicAdd(ar + 3,  e * (float)lo[3]);
    atomicAdd(ar + 4,  e * (float)lo[4]);
    atomicAdd(ar + 5,  e * (float)lo[5]);
    atomicAdd(ar + 6,  e * (float)lo[6]);
    atomicAdd(ar + 7,  e * (float)lo[7]);
    atomicAdd(ar + 8,  e * (float)hi[0]);
    atomicAdd(ar + 9,  e * (float)hi[1]);
    atomicAdd(ar + 10, e * (float)hi[2]);
    atomicAdd(ar + 11, e * (float)hi[3]);
    atomicAdd(ar + 12, e * (float)hi[4]);
    atomicAdd(ar + 13, e * (float)hi[5]);
    atomicAdd(ar + 14, e * (float)hi[6]);
    atomicAdd(ar + 15, e * (float)hi[7]);
  }
  __syncthreads();
  // epilogue: normalize, emit fp16 + invn for next stage
  for (int it = 0; it < 4; ++it) {
    int node = (tid >> 4) + (it << 4);
    int k = tid & 15;
    int gn = n0 + node;
    float o = acc[node * 17 + k] / ssum[node];
    hf oh = (hf)o;
    float of = (float)oh;
    float m2 = of * of;
    m2 += __shfl_xor(m2, 1); m2 += __shfl_xor(m2, 2);
    m2 += __shfl_xor(m2, 4); m2 += __shfl_xor(m2, 8);
    if (gn < NN) {
      hxo[gn * HID + k] = oh;
      if (k == 0) invno[gn] = rsqrtf(fmaxf(m2, 1e-24f));
    }
  }
}

// ---------------- classifier + log_softmax (fp16 input) ---------------------
__global__ __launch_bounds__(256) void k_cls(
    const hf* __restrict__ x, const float* __restrict__ W2,
    const float* __restrict__ b2, float* __restrict__ out) {
  __shared__ float sW[HID * NCLS];
  __shared__ float sb[NCLS];
  for (int i = threadIdx.x; i < HID * NCLS; i += 256) sW[i] = W2[i];
  if (threadIdx.x < NCLS) sb[threadIdx.x] = b2[threadIdx.x];
  __syncthreads();
  int i = blockIdx.x * 256 + threadIdx.x;
  if (i >= NN) return;
  float xi[HID];
  const hf2* X = (const hf2*)(x + (size_t)i * HID);
#pragma unroll
  for (int r = 0; r < 8; ++r) {
    hf2 v = X[r];
    xi[2 * r] = (float)v.x; xi[2 * r + 1] = (float)v.y;
  }
  float logit[NCLS];
  float mx = -1e30f;
#pragma unroll
  for (int c = 0; c < NCLS; ++c) {
    float acc = sb[c];
#pragma unroll
    for (int kk = 0; kk < HID; ++kk) acc = fmaf(xi[kk], sW[kk * NCLS + c], acc);
    logit[c] = acc;
    mx = fmaxf(mx, acc);
  }
  float ssum = 0.0f;
#pragma unroll
  for (int c = 0; c < NCLS; ++c) ssum += __expf(logit[c] - mx);
  float lse = mx + logf(ssum);
  float* o = out + (size_t)i * NCLS;
#pragma unroll
  for (int c = 0; c < NCLS; ++c) o[c] = logit[c] - lse;
}

extern "C" void kernel_launch(void* const* d_in, const int* in_sizes, int n_in,
                              void* d_out, int out_size, void* d_ws, size_t ws_size,
                              hipStream_t stream) {
  const int*   x_ids = (const int*)d_in[0];
  const int*   ei    = (const int*)d_in[1];   // [2, E]: row0 = src, row1 = dst
  const float* emb   = (const float*)d_in[2];
  const float* W1    = (const float*)d_in[3];
  const float* b1    = (const float*)d_in[4];
  const float* beta2 = (const float*)d_in[5];
  const float* W2    = (const float*)d_in[6];
  const float* b2    = (const float*)d_in[7];
  float* out = (float*)d_out;

  // workspace (~20.1 MB): strm stays LIVE through both props now (no aliasing)
  hf*    hx0   = (hf*)d_ws;                       // [NN*HID] 3.2 MB (16B aligned)
  hf*    hx1   = hx0 + (size_t)NN * HID;          // [NN*HID] 3.2 MB
  float* invn0 = (float*)(hx1 + (size_t)NN * HID);// [NN] 0.4 MB
  float* invn1 = invn0 + NN;                      // [NN] 0.4 MB
  unsigned* strm = (unsigned*)(invn1 + NN);       // [NE] 12.8 MB
  int* gcount = (int*)(strm + NE);                // [NBK2]
  int* gbase  = gcount + NBK2;                    // [NBK2]
  int* gcur   = gbase + NBK2;                     // [NBK2]

  const int* esrc = ei;
  const int* edst = ei + NE;

  const int gN = (NN + 255) / 256;
  const int gM = (NN + 15) / 16;

  // bucket build (64-node buckets; self-loops handled inside k_prop)
  k_zero<<<(NBK2 + 255) / 256, 256, 0, stream>>>(gcount, NBK2);
  kA<<<NBLKC, TB, 0, stream>>>(edst, gcount);
  kB<<<1, TB, 0, stream>>>(gcount, gbase, gcur);
  kC<<<NBLKC, TB, 0, stream>>>(esrc, edst, gcur, strm);

  // features (fp16 + invn)
  k_embed_mlp<<<gM, 256, 0, stream>>>(x_ids, emb, W1, b1, hx0, invn0);

  // prop1 (beta = 1.0), prop2 (beta = beta2) — bucket-centric, reads strm
  k_prop<<<NBK2, TPB, 0, stream>>>(gcount, gbase, strm, hx0, invn0, nullptr, hx1, invn1);
  k_prop<<<NBK2, TPB, 0, stream>>>(gcount, gbase, strm, hx1, invn1, beta2, hx0, invn0);

  k_cls<<<gN, 256, 0, stream>>>(hx0, W2, b2, out);
}

// Round 11
// 199.963 us; speedup vs baseline: 3.8089x; 3.8089x over previous
//
#include <hip/hip_runtime.h>
#include <math.h>

#define NN    100000
#define NE    3200000
#define FEAT  128
#define HID   16
#define NCLS  20
#define NBKT  391            // ceil(NN/256) coarse buckets (dst >> 8)
#define NBLKC 512            // blocks for bucket count/scatter
#define TB    1024           // threads/block for kA/kC/kD
#define CHNK  ((NE + NBLKC - 1) / NBLKC)   // 6250 edges per kC block
#define KC_SL 7              // ceil(CHNK/TB) register-cache slots
#define KD_SL 9              // 9*TB=9216 >= max coarse-bucket degree (~8.6K)

typedef _Float16 hf;
typedef _Float16 hf2 __attribute__((ext_vector_type(2)));

__device__ __forceinline__ float dot2f(hf2 a, hf2 b) {
#if defined(__has_builtin) && __has_builtin(__builtin_amdgcn_fdot2)
  return __builtin_amdgcn_fdot2(a, b, 0.0f, false);
#else
  return fmaf((float)a.y, (float)b.y, (float)a.x * (float)b.x);
#endif
}

// ---- embedding gather + MLP -> fp16 features + invn ------------------------
__global__ __launch_bounds__(256) void k_embed_mlp(
    const int* __restrict__ ids, const float* __restrict__ emb,
    const float* __restrict__ W1, const float* __restrict__ b1,
    hf* __restrict__ hx, float* __restrict__ invn) {
  __shared__ float sW[FEAT * HID];
  for (int i = threadIdx.x; i < FEAT * HID; i += 256) sW[i] = W1[i];
  __syncthreads();
  int node = blockIdx.x * 16 + (threadIdx.x >> 4);
  int k = threadIdx.x & 15;
  if (node >= NN) return;
  const float* er = emb + (size_t)ids[node] * FEAT;
  float acc = b1[k];
#pragma unroll 8
  for (int j = 0; j < FEAT; ++j) acc = fmaf(er[j], sW[j * HID + k], acc);
  acc = fmaxf(acc, 0.0f);
  hf h = (hf)acc;
  float a = (float)h;
  float n2 = a * a;
  n2 += __shfl_xor(n2, 1); n2 += __shfl_xor(n2, 2);
  n2 += __shfl_xor(n2, 4); n2 += __shfl_xor(n2, 8);
  hx[node * HID + k] = h;
  if (k == 0) invn[node] = rsqrtf(fmaxf(n2, 1e-24f));  // 1/max(||x||,1e-12)
}

// ---------------- CSR build: bucketed counting sort -------------------------
__global__ __launch_bounds__(256) void k_zero(int* __restrict__ c, int n) {
  int i = blockIdx.x * 256 + threadIdx.x;
  if (i < n) c[i] = 0;
}

__global__ __launch_bounds__(TB) void kA(
    const int* __restrict__ edst, int* __restrict__ gcount) {
  __shared__ int h[NBKT];
  for (int i = threadIdx.x; i < NBKT; i += TB) h[i] = 0;
  __syncthreads();
  int s0 = blockIdx.x * CHNK, s1 = min(NE, s0 + CHNK);
  for (int i = s0 + threadIdx.x; i < s1; i += TB)
    atomicAdd(&h[__builtin_nontemporal_load(edst + i) >> 8], 1);
  __syncthreads();
  for (int i = threadIdx.x; i < NBKT; i += TB)
    if (h[i]) atomicAdd(&gcount[i], h[i]);
}

__global__ __launch_bounds__(512) void kB(
    const int* __restrict__ gcount, int* __restrict__ gbase,
    int* __restrict__ gcur, int* __restrict__ rowptr) {
  __shared__ int sd[512];
  int tid = threadIdx.x;
  int v = (tid < NBKT) ? gcount[tid] : 0;
  sd[tid] = v;
  __syncthreads();
  for (int off = 1; off < 512; off <<= 1) {
    int t = (tid >= off) ? sd[tid - off] : 0;
    __syncthreads();
    sd[tid] += t;
    __syncthreads();
  }
  if (tid < NBKT) { int b = sd[tid] - v; gbase[tid] = b; gcur[tid] = b; }
  if (tid == 0) rowptr[NN] = NE;
}

// kC: block-local LDS counting sort, COALESCED run write-out. Edge data read
// ONCE from global into registers (fixed-trip unrolled loops -> static idx).
__global__ __launch_bounds__(TB) void kC(
    const int* __restrict__ esrc, const int* __restrict__ edst,
    int* __restrict__ gcur, unsigned* __restrict__ strm) {
  __shared__ int h[NBKT];            // counts, then scatter cursors
  __shared__ int lofs[NBKT + 1];     // local exclusive offsets
  __shared__ int basel[NBKT];        // reserved global run bases
  __shared__ int sd[512];
  __shared__ unsigned lsort[CHNK];   // 25 KB locally sorted chunk
  int tid = threadIdx.x;
  for (int i = tid; i < NBKT; i += TB) h[i] = 0;
  __syncthreads();
  int s0 = blockIdx.x * CHNK, s1 = min(NE, s0 + CHNK);
  int total = s1 - s0;
  int dc[KC_SL], sc[KC_SL];
#pragma unroll
  for (int j = 0; j < KC_SL; ++j) {
    int i = s0 + tid + j * TB;
    if (i < s1) {
      int d = __builtin_nontemporal_load(edst + i);
      dc[j] = d;
      sc[j] = __builtin_nontemporal_load(esrc + i);
      atomicAdd(&h[d >> 8], 1);
    }
  }
  __syncthreads();                                   // hist complete
  int v = (tid < NBKT) ? h[tid] : 0;
  if (tid < 512) sd[tid] = v;
  __syncthreads();
  for (int off = 1; off < 512; off <<= 1) {
    int t = (tid < 512 && tid >= off) ? sd[tid - off] : 0;
    __syncthreads();
    if (tid < 512) sd[tid] += t;
    __syncthreads();
  }
  if (tid < NBKT) {
    lofs[tid] = sd[tid] - v;
    basel[tid] = v ? atomicAdd(&gcur[tid], v) : 0;
  }
  if (tid == 0) lofs[NBKT] = total;
  __syncthreads();                                   // scan consumed
  for (int i = tid; i < NBKT; i += TB) h[i] = 0;     // cursors
  __syncthreads();
#pragma unroll
  for (int j = 0; j < KC_SL; ++j) {
    int i = s0 + tid + j * TB;
    if (i < s1) {
      int d = dc[j];
      int b = d >> 8;
      int p = lofs[b] + atomicAdd(&h[b], 1);
      lsort[p] = (unsigned)sc[j] | ((unsigned)(d & 255) << 17);
    }
  }
  __syncthreads();                                   // lsort ready
  for (int j = tid; j < total; j += TB) {
    int lo = 0, hi = NBKT;                           // lofs[lo]<=j<lofs[hi]
    while (hi - lo > 1) {
      int mid = (lo + hi) >> 1;
      if (lofs[mid] <= j) lo = mid; else hi = mid;
    }
    strm[basel[lo] + (j - lofs[lo])] = lsort[j];
  }
}

// kD: fine sort within bucket. strm read ONCE into registers (9 static slots,
// global-reread fallback for the ~never n>9216 case).
__global__ __launch_bounds__(TB) void kD(
    const int* __restrict__ gcount, const int* __restrict__ gbase,
    const unsigned* __restrict__ strm, int* __restrict__ rowptr,
    int* __restrict__ col) {
  __shared__ int cnt[256];
  __shared__ int cur[256];
  __shared__ int sd[256];
  int b = blockIdx.x, tid = threadIdx.x;
  int base = gbase[b], n = gcount[b];
  if (tid < 256) cnt[tid] = 0;
  __syncthreads();
  unsigned wc[KD_SL];
#pragma unroll
  for (int j = 0; j < KD_SL; ++j) {
    int i = tid + j * TB;
    if (i < n) {
      unsigned w = strm[base + i];
      wc[j] = w;
      atomicAdd(&cnt[w >> 17], 1);
    }
  }
  for (int i = tid + KD_SL * TB; i < n; i += TB)     // overflow (~never)
    atomicAdd(&cnt[strm[base + i] >> 17], 1);
  __syncthreads();
  int v = (tid < 256) ? cnt[tid] : 0;
  if (tid < 256) sd[tid] = v;
  __syncthreads();
  for (int off = 1; off < 256; off <<= 1) {
    int t = (tid >= off && tid < 256) ? sd[tid - off] : 0;
    __syncthreads();
    if (tid < 256) sd[tid] += t;
    __syncthreads();
  }
  if (tid < 256) {
    int excl = sd[tid] - v;
    cur[tid] = excl;
    int node = (b << 8) + tid;
    if (node < NN) rowptr[node] = base + excl;
  }
  __syncthreads();
#pragma unroll
  for (int j = 0; j < KD_SL; ++j) {
    int i = tid + j * TB;
    if (i < n) {
      unsigned w = wc[j];
      int p = atomicAdd(&cur[w >> 17], 1);
      col[base + p] = (int)(w & 0x1FFFFu);
    }
  }
  for (int i = tid + KD_SL * TB; i < n; i += TB) {   // overflow (~never)
    unsigned w = strm[base + i];
    int p = atomicAdd(&cur[w >> 17], 1);
    col[base + p] = (int)(w & 0x1FFFFu);
  }
}

// ---- fused AGNN prop: 8 lanes/node, fdot2, depth-1 pipelined gathers -------
// out_i = (e_self*x_i + sum_j e_ij*x_j) / (e_self + sum_j e_ij)
// e_ij = exp(beta * (sum_k xn_i[k]*x_j[k]) * invn_j)
#define PROP_COMPUTE4(c0, c1, c2, c3, j0, j1, j2, j3)                        \
  {                                                                          \
    float r0 = dot2f(xdn2, c0);                                              \
    float r1 = dot2f(xdn2, c1);                                              \
    float r2 = dot2f(xdn2, c2);                                              \
    float r3 = dot2f(xdn2, c3);                                              \
    r0 += __shfl_xor(r0, 1); r1 += __shfl_xor(r1, 1);                        \
    r2 += __shfl_xor(r2, 1); r3 += __shfl_xor(r3, 1);                        \
    r0 += __shfl_xor(r0, 2); r1 += __shfl_xor(r1, 2);                        \
    r2 += __shfl_xor(r2, 2); r3 += __shfl_xor(r3, 2);                        \
    r0 += __shfl_xor(r0, 4); r1 += __shfl_xor(r1, 4);                        \
    r2 += __shfl_xor(r2, 4); r3 += __shfl_xor(r3, 4);                        \
    float e0 = __expf(beta * r0 * j0);                                       \
    float e1 = __expf(beta * r1 * j1);                                       \
    float e2v = __expf(beta * r2 * j2);                                      \
    float e3 = __expf(beta * r3 * j3);                                       \
    s += (e0 + e1) + (e2v + e3);                                             \
    a0 = fmaf(e0, (float)c0.x, a0);  a1 = fmaf(e0, (float)c0.y, a1);         \
    a0 = fmaf(e1, (float)c1.x, a0);  a1 = fmaf(e1, (float)c1.y, a1);         \
    a0 = fmaf(e2v, (float)c2.x, a0); a1 = fmaf(e2v, (float)c2.y, a1);        \
    a0 = fmaf(e3, (float)c3.x, a0);  a1 = fmaf(e3, (float)c3.y, a1);         \
  }

__global__ __launch_bounds__(256) void k_prop(
    const int* __restrict__ rowptr, const int* __restrict__ col,
    const hf* __restrict__ hx, const float* __restrict__ invn,
    const float* __restrict__ beta_p,
    hf* __restrict__ hxo, float* __restrict__ invno) {
  int node = blockIdx.x * 32 + (threadIdx.x >> 3);
  int l = threadIdx.x & 7;                 // lane owns features 2l, 2l+1
  if (node >= NN) return;
  float beta = beta_p ? beta_p[0] : 1.0f;
  const hf2* H = (const hf2*)hx;
  hf2 xi2 = H[node * 8 + l];
  float x0 = (float)xi2.x, x1 = (float)xi2.y;
  float invi = invn[node];
  float n2 = x0 * x0 + x1 * x1;
  n2 += __shfl_xor(n2, 1); n2 += __shfl_xor(n2, 2); n2 += __shfl_xor(n2, 4);
  hf2 xdn2; xdn2.x = (hf)(x0 * invi); xdn2.y = (hf)(x1 * invi);
  float dself = n2 * invi * invi;          // ||xn_i||^2
  float es = __expf(beta * dself);
  float s = es;
  float a0 = es * x0, a1 = es * x1;        // acc (2 features per lane)
  int e = rowptr[node], e2 = rowptr[node + 1];
  int u0, u1, u2, u3; hf2 f0, f1, f2, f3; float i0, i1, i2, i3;
  if (e + 4 <= e2) {                       // prologue: load group 0
    u0 = col[e]; u1 = col[e + 1]; u2 = col[e + 2]; u3 = col[e + 3];
    f0 = H[u0 * 8 + l]; f1 = H[u1 * 8 + l];
    f2 = H[u2 * 8 + l]; f3 = H[u3 * 8 + l];
    i0 = invn[u0]; i1 = invn[u1]; i2 = invn[u2]; i3 = invn[u3];
  }
  for (; e + 8 <= e2; e += 4) {            // steady state: prefetch next 4
    hf2 c0 = f0, c1 = f1, c2 = f2, c3 = f3;
    float j0 = i0, j1 = i1, j2 = i2, j3 = i3;
    u0 = col[e + 4]; u1 = col[e + 5]; u2 = col[e + 6]; u3 = col[e + 7];
    f0 = H[u0 * 8 + l]; f1 = H[u1 * 8 + l];
    f2 = H[u2 * 8 + l]; f3 = H[u3 * 8 + l];
    i0 = invn[u0]; i1 = invn[u1]; i2 = invn[u2]; i3 = invn[u3];
    PROP_COMPUTE4(c0, c1, c2, c3, j0, j1, j2, j3);
  }
  if (e + 4 <= e2) {                       // drain pipelined group
    PROP_COMPUTE4(f0, f1, f2, f3, i0, i1, i2, i3);
    e += 4;
  }
  for (; e < e2; ++e) {                    // tail singles
    int u = col[e];
    hf2 b = H[u * 8 + l];
    float r = dot2f(xdn2, b);
    r += __shfl_xor(r, 1); r += __shfl_xor(r, 2); r += __shfl_xor(r, 4);
    float ee = __expf(beta * r * invn[u]);
    s += ee;
    a0 = fmaf(ee, (float)b.x, a0); a1 = fmaf(ee, (float)b.y, a1);
  }
  float inv_s = 1.0f / s;
  hf2 o; o.x = (hf)(a0 * inv_s); o.y = (hf)(a1 * inv_s);
  float g0 = (float)o.x, g1 = (float)o.y;
  float m2 = g0 * g0 + g1 * g1;
  m2 += __shfl_xor(m2, 1); m2 += __shfl_xor(m2, 2); m2 += __shfl_xor(m2, 4);
  ((hf2*)hxo)[node * 8 + l] = o;
  if (l == 0) invno[node] = rsqrtf(fmaxf(m2, 1e-24f));
}

// ---------------- classifier + log_softmax (fp16 input) ---------------------
__global__ __launch_bounds__(256) void k_cls(
    const hf* __restrict__ x, const float* __restrict__ W2,
    const float* __restrict__ b2, float* __restrict__ out) {
  __shared__ float sW[HID * NCLS];
  __shared__ float sb[NCLS];
  for (int i = threadIdx.x; i < HID * NCLS; i += 256) sW[i] = W2[i];
  if (threadIdx.x < NCLS) sb[threadIdx.x] = b2[threadIdx.x];
  __syncthreads();
  int i = blockIdx.x * 256 + threadIdx.x;
  if (i >= NN) return;
  float xi[HID];
  const hf2* X = (const hf2*)(x + (size_t)i * HID);
#pragma unroll
  for (int r = 0; r < 8; ++r) {
    hf2 v = X[r];
    xi[2 * r] = (float)v.x; xi[2 * r + 1] = (float)v.y;
  }
  float logit[NCLS];
  float mx = -1e30f;
#pragma unroll
  for (int c = 0; c < NCLS; ++c) {
    float acc = sb[c];
#pragma unroll
    for (int kk = 0; kk < HID; ++kk) acc = fmaf(xi[kk], sW[kk * NCLS + c], acc);
    logit[c] = acc;
    mx = fmaxf(mx, acc);
  }
  float ssum = 0.0f;
#pragma unroll
  for (int c = 0; c < NCLS; ++c) ssum += __expf(logit[c] - mx);
  float lse = mx + logf(ssum);
  float* o = out + (size_t)i * NCLS;
#pragma unroll
  for (int c = 0; c < NCLS; ++c) o[c] = logit[c] - lse;
}

extern "C" void kernel_launch(void* const* d_in, const int* in_sizes, int n_in,
                              void* d_out, int out_size, void* d_ws, size_t ws_size,
                              hipStream_t stream) {
  const int*   x_ids = (const int*)d_in[0];
  const int*   ei    = (const int*)d_in[1];   // [2, E]: row0 = src, row1 = dst
  const float* emb   = (const float*)d_in[2];
  const float* W1    = (const float*)d_in[3];
  const float* b1    = (const float*)d_in[4];
  const float* beta2 = (const float*)d_in[5];
  const float* W2    = (const float*)d_in[6];
  const float* b2    = (const float*)d_in[7];
  float* out = (float*)d_out;

  // workspace: [strm NE u32 | col NE | rowptr | gcount | gbase | gcur]
  // strm is dead after kD; fp16 feature pipeline aliases it (7.2 MB < 12.8 MB).
  unsigned* strm = (unsigned*)d_ws;
  int* col    = (int*)d_ws + NE;
  int* rowptr = col + NE;
  int* gcount = rowptr + (NN + 1);
  int* gbase  = gcount + NBKT;
  int* gcur   = gbase + NBKT;
  hf*    hx0   = (hf*)d_ws;                      // [NN*HID] 3.2 MB
  hf*    hx1   = hx0 + (size_t)NN * HID;         // [NN*HID] 3.2 MB
  float* invn0 = (float*)(hx1 + (size_t)NN * HID);   // [NN] 0.4 MB
  float* invn1 = invn0 + NN;                     // [NN] 0.4 MB

  const int* esrc = ei;
  const int* edst = ei + NE;

  const int gN = (NN + 255) / 256;
  const int gM = (NN + 15) / 16;
  const int gP = (NN + 31) / 32;

  // CSR build (self-loops handled analytically in k_prop)
  k_zero<<<2, 256, 0, stream>>>(gcount, NBKT);
  kA<<<NBLKC, TB, 0, stream>>>(edst, gcount);
  kB<<<1, 512, 0, stream>>>(gcount, gbase, gcur, rowptr);
  kC<<<NBLKC, TB, 0, stream>>>(esrc, edst, gcur, strm);
  kD<<<NBKT, TB, 0, stream>>>(gcount, gbase, strm, rowptr, col);

  // features (fp16 + invn), aliasing strm (dead after kD)
  k_embed_mlp<<<gM, 256, 0, stream>>>(x_ids, emb, W1, b1, hx0, invn0);

  // prop1 (beta = 1.0), prop2 (beta = beta2)
  k_prop<<<gP, 256, 0, stream>>>(rowptr, col, hx0, invn0, nullptr, hx1, invn1);
  k_prop<<<gP, 256, 0, stream>>>(rowptr, col, hx1, invn1, beta2, hx0, invn0);

  k_cls<<<gN, 256, 0, stream>>>(hx0, W2, b2, out);
}